// Round 1
// baseline (6018.174 us; speedup 1.0000x reference)
//
#include <hip/hip_runtime.h>
#include <cmath>

#define Bn 64
#define Tn 512
#define Dn 400
#define Ln 25
#define Hn 200
#define G4n 800
#define TCn 64
#define NCH 8
#define NPADn 832

// ---- workspace layout (float offsets); total ~86.1 MB ----
constexpr size_t OFF_WIHT = 0;                                  // [2][400][832]
constexpr size_t OFF_WHHP = OFF_WIHT + (size_t)2*Dn*NPADn;      // [2][200][200][4]
constexpr size_t OFF_BSUM = OFF_WHHP + (size_t)2*Hn*Hn*4;       // [2][800]
constexpr size_t OFF_G    = OFF_BSUM + (size_t)2*G4n;           // [2][64][64][200][4]
constexpr size_t OFF_HCAT = OFF_G + (size_t)2*Bn*TCn*G4n;       // [64][512][400]
constexpr size_t OFF_E    = OFF_HCAT + (size_t)Bn*Tn*2*Hn;      // [64][512][25]
constexpr size_t OFF_HST  = OFF_E + (size_t)Bn*Tn*Ln;           // [2][64][200]
constexpr size_t OFF_CST  = OFF_HST + (size_t)2*Bn*Hn;          // [2][64][200]
constexpr size_t OFF_PART = OFF_CST + (size_t)2*Bn*Hn;          // [64]

__device__ __forceinline__ float sigf(float x) { return 1.0f / (1.0f + expf(-x)); }

// ---------------- prep: transpose/pack weights, zero state ----------------
__global__ void prep_kernel(const float* __restrict__ Wih_f, const float* __restrict__ Whh_f,
                            const float* __restrict__ bih_f, const float* __restrict__ bhh_f,
                            const float* __restrict__ Wih_b, const float* __restrict__ Whh_b,
                            const float* __restrict__ bih_b, const float* __restrict__ bhh_b,
                            float* __restrict__ ws) {
    int tid = blockIdx.x * blockDim.x + threadIdx.x;
    int nth = gridDim.x * blockDim.x;
    float* WihT = ws + OFF_WIHT;
    float* WhhP = ws + OFF_WHHP;
    float* bsum = ws + OFF_BSUM;
    float* hst  = ws + OFF_HST;
    float* cst  = ws + OFF_CST;
    for (int i = tid; i < 2*Dn*NPADn; i += nth) {
        int d = i / (Dn*NPADn); int r = i % (Dn*NPADn); int k = r / NPADn; int g = r % NPADn;
        const float* W = d ? Wih_b : Wih_f;
        WihT[i] = (g < G4n) ? W[(size_t)g*Dn + k] : 0.0f;
    }
    for (int i = tid; i < 2*Hn*Hn*4; i += nth) {
        int d = i / (Hn*Hn*4); int r = i % (Hn*Hn*4);
        int j = r / (Hn*4); int r2 = r % (Hn*4); int k = r2 / 4; int q = r2 % 4;
        const float* W = d ? Whh_b : Whh_f;
        WhhP[i] = W[(size_t)(q*Hn + k)*Hn + j];
    }
    for (int i = tid; i < 2*G4n; i += nth) {
        int d = i / G4n; int g = i % G4n;
        bsum[i] = d ? (bih_b[g] + bhh_b[g]) : (bih_f[g] + bhh_f[g]);
    }
    for (int i = tid; i < 2*Bn*Hn; i += nth) { hst[i] = 0.0f; cst[i] = 0.0f; }
}

// ---------------- input projection GEMM for one time-chunk (both dirs) ----------------
// grid: (13 N-tiles, 64 batch, 2 dir), 256 threads; BM=64(one b's 64 t), BN=64, BK=16
__global__ __launch_bounds__(256) void gemm_kernel(const float* __restrict__ X,
                                                   float* __restrict__ ws, int chunk) {
    const float* WihT = ws + OFF_WIHT;
    const float* bsum = ws + OFF_BSUM;
    float* G = ws + OFF_G;
    int d = blockIdx.z;
    int b = blockIdx.y;
    int g0 = blockIdx.x * 64;
    int tid = threadIdx.x;
    int tx = tid % 16, ty = tid / 16;
    int t_base = (d == 0) ? chunk * TCn : (Tn - (chunk + 1) * TCn);
    const float* Arow = X + ((size_t)b * Tn + t_base) * Dn;
    const float* Bmat = WihT + (size_t)d * Dn * NPADn;

    __shared__ float As[16][68];
    __shared__ float Bs[16][68];
    float acc[4][4] = {{0.f}};
    int lr = tid / 4, lk = tid % 4;   // A load: row, k-quad
    int bk = tid / 16, bg = tid % 16; // B load: k row, g-quad

    for (int kt = 0; kt < Dn; kt += 16) {
        float4 a4 = *(const float4*)(Arow + (size_t)lr * Dn + kt + lk * 4);
        float4 b4 = *(const float4*)(Bmat + (size_t)(kt + bk) * NPADn + g0 + bg * 4);
        __syncthreads();
        As[lk*4+0][lr] = a4.x; As[lk*4+1][lr] = a4.y;
        As[lk*4+2][lr] = a4.z; As[lk*4+3][lr] = a4.w;
        *(float4*)&Bs[bk][bg*4] = b4;
        __syncthreads();
        #pragma unroll
        for (int kk = 0; kk < 16; ++kk) {
            float4 af = *(const float4*)&As[kk][ty*4];
            float4 bf = *(const float4*)&Bs[kk][tx*4];
            acc[0][0] += af.x*bf.x; acc[0][1] += af.x*bf.y; acc[0][2] += af.x*bf.z; acc[0][3] += af.x*bf.w;
            acc[1][0] += af.y*bf.x; acc[1][1] += af.y*bf.y; acc[1][2] += af.y*bf.z; acc[1][3] += af.y*bf.w;
            acc[2][0] += af.z*bf.x; acc[2][1] += af.z*bf.y; acc[2][2] += af.z*bf.z; acc[2][3] += af.z*bf.w;
            acc[3][0] += af.w*bf.x; acc[3][1] += af.w*bf.y; acc[3][2] += af.w*bf.z; acc[3][3] += af.w*bf.w;
        }
    }
    #pragma unroll
    for (int ii = 0; ii < 4; ++ii) {
        int tloc = ty * 4 + ii;
        #pragma unroll
        for (int jj = 0; jj < 4; ++jj) {
            int g = g0 + tx * 4 + jj;
            if (g < G4n) {
                int k = g % Hn, q = g / Hn;
                G[(((size_t)d*Bn + b)*TCn + tloc)*G4n + k*4 + q] = acc[ii][jj] + bsum[d*G4n + g];
            }
        }
    }
}

// ---------------- LSTM recurrence for one time-chunk ----------------
// grid: 64 WGs (32 fwd pairs + 32 bwd pairs), 256 threads; thread k<200 owns h-index k
__global__ __launch_bounds__(256) void rec_kernel(const float* __restrict__ mask,
                                                  float* __restrict__ ws, int chunk) {
    const float* WhhP = ws + OFF_WHHP;
    const float* G = ws + OFF_G;
    float* Hcat = ws + OFF_HCAT;
    float* hst = ws + OFF_HST;
    float* cst = ws + OFF_CST;
    int w = blockIdx.x;
    int d = w / 32;
    int pr = w % 32;
    int b0 = pr * 2, b1 = b0 + 1;
    int k = threadIdx.x;
    __shared__ float hbuf[2][2][Hn];
    float hr0 = 0.f, hr1 = 0.f, cr0 = 0.f, cr1 = 0.f;
    if (k < Hn) {
        hr0 = hst[(size_t)(d*Bn + b0)*Hn + k]; hr1 = hst[(size_t)(d*Bn + b1)*Hn + k];
        cr0 = cst[(size_t)(d*Bn + b0)*Hn + k]; cr1 = cst[(size_t)(d*Bn + b1)*Hn + k];
        hbuf[0][0][k] = hr0; hbuf[0][1][k] = hr1;
    }
    __syncthreads();
    const float* Wd = WhhP + (size_t)d * Hn * Hn * 4 + k * 4;
    int cur = 0;
    for (int s = 0; s < TCn; ++s) {
        int tg, tloc;
        if (d == 0) { tloc = s; tg = chunk * TCn + s; }
        else        { tloc = TCn - 1 - s; tg = Tn - 1 - (chunk * TCn + s); }
        float m0 = mask[(size_t)b0 * Tn + tg];
        float m1 = mask[(size_t)b1 * Tn + tg];
        if (k < Hn) {
            float4 acc0 = *(const float4*)(G + (((size_t)d*Bn + b0)*TCn + tloc)*G4n + k*4);
            float4 acc1 = *(const float4*)(G + (((size_t)d*Bn + b1)*TCn + tloc)*G4n + k*4);
            #pragma unroll 2
            for (int j4 = 0; j4 < Hn/4; ++j4) {
                float4 h0 = *(const float4*)&hbuf[cur][0][j4*4];
                float4 h1 = *(const float4*)&hbuf[cur][1][j4*4];
                float4 w0 = *(const float4*)(Wd + (size_t)(j4*4+0)*Hn*4);
                float4 w1 = *(const float4*)(Wd + (size_t)(j4*4+1)*Hn*4);
                float4 w2 = *(const float4*)(Wd + (size_t)(j4*4+2)*Hn*4);
                float4 w3 = *(const float4*)(Wd + (size_t)(j4*4+3)*Hn*4);
                acc0.x += w0.x*h0.x; acc0.y += w0.y*h0.x; acc0.z += w0.z*h0.x; acc0.w += w0.w*h0.x;
                acc0.x += w1.x*h0.y; acc0.y += w1.y*h0.y; acc0.z += w1.z*h0.y; acc0.w += w1.w*h0.y;
                acc0.x += w2.x*h0.z; acc0.y += w2.y*h0.z; acc0.z += w2.z*h0.z; acc0.w += w2.w*h0.z;
                acc0.x += w3.x*h0.w; acc0.y += w3.y*h0.w; acc0.z += w3.z*h0.w; acc0.w += w3.w*h0.w;
                acc1.x += w0.x*h1.x; acc1.y += w0.y*h1.x; acc1.z += w0.z*h1.x; acc1.w += w0.w*h1.x;
                acc1.x += w1.x*h1.y; acc1.y += w1.y*h1.y; acc1.z += w1.z*h1.y; acc1.w += w1.w*h1.y;
                acc1.x += w2.x*h1.z; acc1.y += w2.y*h1.z; acc1.z += w2.z*h1.z; acc1.w += w2.w*h1.z;
                acc1.x += w3.x*h1.w; acc1.y += w3.y*h1.w; acc1.z += w3.z*h1.w; acc1.w += w3.w*h1.w;
            }
            float i0 = sigf(acc0.x), f0 = sigf(acc0.y), gg0 = tanhf(acc0.z), o0 = sigf(acc0.w);
            float cn0 = f0 * cr0 + i0 * gg0;
            float hn0 = o0 * tanhf(cn0);
            cr0 = m0 * cn0 + (1.f - m0) * cr0;
            hr0 = m0 * hn0 + (1.f - m0) * hr0;
            float i1 = sigf(acc1.x), f1 = sigf(acc1.y), gg1 = tanhf(acc1.z), o1 = sigf(acc1.w);
            float cn1 = f1 * cr1 + i1 * gg1;
            float hn1 = o1 * tanhf(cn1);
            cr1 = m1 * cn1 + (1.f - m1) * cr1;
            hr1 = m1 * hn1 + (1.f - m1) * hr1;
            hbuf[cur ^ 1][0][k] = hr0;
            hbuf[cur ^ 1][1][k] = hr1;
            Hcat[((size_t)b0 * Tn + tg) * (2*Hn) + d*Hn + k] = hr0;
            Hcat[((size_t)b1 * Tn + tg) * (2*Hn) + d*Hn + k] = hr1;
        }
        __syncthreads();
        cur ^= 1;
    }
    if (k < Hn) {
        hst[(size_t)(d*Bn + b0)*Hn + k] = hr0; hst[(size_t)(d*Bn + b1)*Hn + k] = hr1;
        cst[(size_t)(d*Bn + b0)*Hn + k] = cr0; cst[(size_t)(d*Bn + b1)*Hn + k] = cr1;
    }
}

// ---------------- emissions: E = (Hcat @ Wl^T + bl) * mask ----------------
// grid: 256 WGs x 128 rows each
__global__ __launch_bounds__(256) void emis_kernel(const float* __restrict__ mask,
                                                   const float* __restrict__ Wl,
                                                   const float* __restrict__ bl,
                                                   float* __restrict__ ws) {
    const float* Hcat = ws + OFF_HCAT;
    float* E = ws + OFF_E;
    __shared__ float Wls[Ln * 404];
    __shared__ float Hs[16 * 404];
    int tid = threadIdx.x;
    for (int i = tid; i < Ln * 100; i += 256) {
        int l = i / 100, k4 = i % 100;
        *(float4*)&Wls[l*404 + k4*4] = *(const float4*)(Wl + (size_t)l*Dn + k4*4);
    }
    int rbase = blockIdx.x * 128;
    for (int sub = 0; sub < 8; ++sub) {
        int r0 = rbase + sub * 16;
        __syncthreads();
        for (int i = tid; i < 16 * 100; i += 256) {
            int r = i / 100, k4 = i % 100;
            *(float4*)&Hs[r*404 + k4*4] = *(const float4*)(Hcat + (size_t)(r0 + r)*Dn + k4*4);
        }
        __syncthreads();
        for (int o = tid; o < 16 * Ln; o += 256) {
            int r = o / Ln, l = o % Ln;
            float acc = 0.f;
            #pragma unroll 4
            for (int k4 = 0; k4 < 100; ++k4) {
                float4 h = *(const float4*)&Hs[r*404 + k4*4];
                float4 wv = *(const float4*)&Wls[l*404 + k4*4];
                acc += h.x*wv.x + h.y*wv.y + h.z*wv.z + h.w*wv.w;
            }
            int row = r0 + r;            // row == b*T + t
            float m = mask[row];
            E[(size_t)row * Ln + l] = (acc + bl[l]) * m;
        }
    }
}

// ---------------- CRF forward (logZ) + numerator ----------------
__global__ __launch_bounds__(64) void crf_kernel(const float* __restrict__ mask,
                                                 const int* __restrict__ labels,
                                                 const float* __restrict__ trans,
                                                 const float* __restrict__ start,
                                                 const float* __restrict__ endv,
                                                 float* __restrict__ ws) {
    int b = blockIdx.x;
    int l = threadIdx.x;
    const float* E = ws + OFF_E;
    float* part = ws + OFF_PART;
    __shared__ float tr[Ln * Ln];
    __shared__ float al[Ln];
    for (int i = l; i < Ln * Ln; i += 64) tr[i] = trans[i];
    float alpha = -1e30f;
    if (l < Ln) { alpha = start[l] + E[((size_t)b * Tn) * Ln + l]; al[l] = alpha; }
    __syncthreads();
    for (int t = 1; t < Tn; ++t) {
        float mt = mask[(size_t)b * Tn + t];
        if (mt > 0.f) {               // wave-uniform branch
            float nv = alpha;
            if (l < Ln) {
                float v[Ln]; float mx = -1e30f;
                #pragma unroll
                for (int j = 0; j < Ln; ++j) { v[j] = al[j] + tr[j*Ln + l]; mx = fmaxf(mx, v[j]); }
                float s = 0.f;
                #pragma unroll
                for (int j = 0; j < Ln; ++j) s += __expf(v[j] - mx);
                nv = mx + __logf(s) + E[((size_t)b * Tn + t) * Ln + l];
            }
            __syncthreads();
            if (l < Ln) { al[l] = nv; alpha = nv; }
            __syncthreads();
        }
    }
    float v = (l < Ln) ? alpha + endv[l] : -1e30f;
    float mx = v;
    for (int off = 32; off; off >>= 1) mx = fmaxf(mx, __shfl_xor(mx, off));
    float s = (l < Ln) ? __expf(v - mx) : 0.f;
    for (int off = 32; off; off >>= 1) s += __shfl_xor(s, off);
    float logZ = mx + __logf(s);
    // numerator (parallel over t, wave reduce)
    float psum = 0.f, plen = 0.f;
    for (int t = l; t < Tn; t += 64) {
        float mt = mask[(size_t)b * Tn + t];
        plen += mt;
        if (t >= 1 && mt > 0.f) {
            int lt = labels[(size_t)b * Tn + t];
            int lp = labels[(size_t)b * Tn + t - 1];
            psum += E[((size_t)b * Tn + t) * Ln + lt] + tr[lp * Ln + lt];
        }
    }
    for (int off = 32; off; off >>= 1) { psum += __shfl_xor(psum, off); plen += __shfl_xor(plen, off); }
    if (l == 0) {
        int last = (int)(plen + 0.5f) - 1;
        int l0 = labels[(size_t)b * Tn];
        int yl = labels[(size_t)b * Tn + last];
        float num = start[l0] + E[((size_t)b * Tn) * Ln + l0] + psum + endv[yl];
        part[b] = num - logZ;
    }
}

// ---------------- Viterbi ----------------
__global__ __launch_bounds__(64) void vit_kernel(const float* __restrict__ mask,
                                                 const float* __restrict__ trans,
                                                 const float* __restrict__ start,
                                                 const float* __restrict__ endv,
                                                 float* __restrict__ ws,
                                                 float* __restrict__ out) {
    int b = blockIdx.x;
    int l = threadIdx.x;
    const float* E = ws + OFF_E;
    __shared__ float tr[Ln * Ln];
    __shared__ float dl[Ln];
    __shared__ unsigned char ptrs[Tn][Ln];
    __shared__ unsigned char ys[Tn];
    for (int i = l; i < Ln * Ln; i += 64) tr[i] = trans[i];
    float delta = -1e30f;
    if (l < Ln) { delta = start[l] + E[((size_t)b * Tn) * Ln + l]; dl[l] = delta; }
    __syncthreads();
    for (int t = 1; t < Tn; ++t) {
        float mt = mask[(size_t)b * Tn + t];
        float nd = delta; int np = (l < Ln) ? l : 0;
        if (l < Ln && mt > 0.f) {
            float best = -1e30f; int ba = 0;
            #pragma unroll
            for (int j = 0; j < Ln; ++j) {
                float c = dl[j] + tr[j * Ln + l];
                if (c > best) { best = c; ba = j; }  // strict > keeps first index (jnp.argmax)
            }
            nd = best + E[((size_t)b * Tn + t) * Ln + l];
            np = ba;
        }
        __syncthreads();
        if (l < Ln) { dl[l] = nd; ptrs[t][l] = (unsigned char)np; delta = nd; }
        __syncthreads();
    }
    if (l == 0) {
        float best = -1e30f; int y = 0;
        for (int j = 0; j < Ln; ++j) { float c = dl[j] + endv[j]; if (c > best) { best = c; y = j; } }
        ys[Tn - 1] = (unsigned char)y;
        for (int t = Tn - 1; t >= 1; --t) { y = ptrs[t][y]; ys[t - 1] = (unsigned char)y; }
    }
    __syncthreads();
    for (int t = l; t < Tn; t += 64) {
        float mt = mask[(size_t)b * Tn + t];
        out[1 + (size_t)b * Tn + t] = (mt > 0.f) ? (float)ys[t] : 0.f;
    }
}

// ---------------- finalize loss ----------------
__global__ __launch_bounds__(64) void fin_kernel(float* __restrict__ ws, float* __restrict__ out) {
    const float* part = ws + OFF_PART;
    int l = threadIdx.x;
    float v = (l < Bn) ? part[l] : 0.f;
    for (int off = 32; off; off >>= 1) v += __shfl_xor(v, off);
    if (l == 0) out[0] = -v / (float)Bn;
}

extern "C" void kernel_launch(void* const* d_in, const int* in_sizes, int n_in,
                              void* d_out, int out_size, void* d_ws, size_t ws_size,
                              hipStream_t stream) {
    (void)in_sizes; (void)n_in; (void)out_size; (void)ws_size;
    const float* X      = (const float*)d_in[0];
    const float* mask   = (const float*)d_in[1];
    const int*   labels = (const int*)d_in[2];
    const float* Wih_f  = (const float*)d_in[3];
    const float* Whh_f  = (const float*)d_in[4];
    const float* bih_f  = (const float*)d_in[5];
    const float* bhh_f  = (const float*)d_in[6];
    const float* Wih_b  = (const float*)d_in[7];
    const float* Whh_b  = (const float*)d_in[8];
    const float* bih_b  = (const float*)d_in[9];
    const float* bhh_b  = (const float*)d_in[10];
    const float* Wl     = (const float*)d_in[11];
    const float* bl     = (const float*)d_in[12];
    const float* trans  = (const float*)d_in[13];
    const float* start  = (const float*)d_in[14];
    const float* endv   = (const float*)d_in[15];
    float* ws  = (float*)d_ws;
    float* out = (float*)d_out;

    prep_kernel<<<128, 256, 0, stream>>>(Wih_f, Whh_f, bih_f, bhh_f,
                                         Wih_b, Whh_b, bih_b, bhh_b, ws);
    for (int c = 0; c < NCH; ++c) {
        gemm_kernel<<<dim3(13, 64, 2), 256, 0, stream>>>(X, ws, c);
        rec_kernel<<<64, 256, 0, stream>>>(mask, ws, c);
    }
    emis_kernel<<<256, 256, 0, stream>>>(mask, Wl, bl, ws);
    crf_kernel<<<64, 64, 0, stream>>>(mask, labels, trans, start, endv, ws);
    vit_kernel<<<64, 64, 0, stream>>>(mask, trans, start, endv, ws, out);
    fin_kernel<<<1, 64, 0, stream>>>(ws, out);
}

// Round 2
// 5003.140 us; speedup vs baseline: 1.2029x; 1.2029x over previous
//
#include <hip/hip_runtime.h>
#include <cmath>

#define Bn 64
#define Tn 512
#define Dn 400
#define Ln 25
#define Hn 200
#define G4n 800
#define TCn 64
#define NCH 8
#define NPADn 832

// ---- workspace layout (float offsets); total ~86.1 MB ----
constexpr size_t OFF_WIHT = 0;                                  // [2][400][832]
constexpr size_t OFF_WHHP = OFF_WIHT + (size_t)2*Dn*NPADn;      // [2][200][200][4]
constexpr size_t OFF_BSUM = OFF_WHHP + (size_t)2*Hn*Hn*4;       // [2][800]
constexpr size_t OFF_G    = OFF_BSUM + (size_t)2*G4n;           // [2][64][64][200][4]
constexpr size_t OFF_HCAT = OFF_G + (size_t)2*Bn*TCn*G4n;       // [64][512][400]
constexpr size_t OFF_E    = OFF_HCAT + (size_t)Bn*Tn*2*Hn;      // [64][512][25]
constexpr size_t OFF_HST  = OFF_E + (size_t)Bn*Tn*Ln;           // [2][64][200]
constexpr size_t OFF_CST  = OFF_HST + (size_t)2*Bn*Hn;          // [2][64][200]
constexpr size_t OFF_PART = OFF_CST + (size_t)2*Bn*Hn;          // [64]

__device__ __forceinline__ float sigf(float x) { return 1.0f / (1.0f + expf(-x)); }

// ---------------- prep: transpose/pack weights, zero state ----------------
__global__ void prep_kernel(const float* __restrict__ Wih_f, const float* __restrict__ Whh_f,
                            const float* __restrict__ bih_f, const float* __restrict__ bhh_f,
                            const float* __restrict__ Wih_b, const float* __restrict__ Whh_b,
                            const float* __restrict__ bih_b, const float* __restrict__ bhh_b,
                            float* __restrict__ ws) {
    int tid = blockIdx.x * blockDim.x + threadIdx.x;
    int nth = gridDim.x * blockDim.x;
    float* WihT = ws + OFF_WIHT;
    float* WhhP = ws + OFF_WHHP;
    float* bsum = ws + OFF_BSUM;
    float* hst  = ws + OFF_HST;
    float* cst  = ws + OFF_CST;
    for (int i = tid; i < 2*Dn*NPADn; i += nth) {
        int d = i / (Dn*NPADn); int r = i % (Dn*NPADn); int k = r / NPADn; int g = r % NPADn;
        const float* W = d ? Wih_b : Wih_f;
        WihT[i] = (g < G4n) ? W[(size_t)g*Dn + k] : 0.0f;
    }
    for (int i = tid; i < 2*Hn*Hn*4; i += nth) {
        int d = i / (Hn*Hn*4); int r = i % (Hn*Hn*4);
        int j = r / (Hn*4); int r2 = r % (Hn*4); int k = r2 / 4; int q = r2 % 4;
        const float* W = d ? Whh_b : Whh_f;
        WhhP[i] = W[(size_t)(q*Hn + k)*Hn + j];
    }
    for (int i = tid; i < 2*G4n; i += nth) {
        int d = i / G4n; int g = i % G4n;
        bsum[i] = d ? (bih_b[g] + bhh_b[g]) : (bih_f[g] + bhh_f[g]);
    }
    for (int i = tid; i < 2*Bn*Hn; i += nth) { hst[i] = 0.0f; cst[i] = 0.0f; }
}

// ---------------- input projection GEMM for one time-chunk (both dirs) ----------------
// grid: (13 N-tiles, 32 b-pairs, 2 dir), 256 threads; BM=128 (2 b x 64 t), BN=64, BK=16
__global__ __launch_bounds__(256) void gemm_kernel(const float* __restrict__ X,
                                                   float* __restrict__ ws, int chunk) {
    const float* WihT = ws + OFF_WIHT;
    const float* bsum = ws + OFF_BSUM;
    float* G = ws + OFF_G;
    int d = blockIdx.z;
    int bp = blockIdx.y;          // batch pair
    int g0 = blockIdx.x * 64;
    int tid = threadIdx.x;
    int tx = tid % 16, ty = tid / 16;
    int t_base = (d == 0) ? chunk * TCn : (Tn - (chunk + 1) * TCn);
    const float* Bmat = WihT + (size_t)d * Dn * NPADn;

    __shared__ float As[16][136];
    __shared__ float Bs[16][68];
    float acc[8][4] = {{0.f}};
    int lr = tid / 2, lk = tid % 2;   // A load: row in [0,128), k-octet
    int bk = tid / 16, bg = tid % 16; // B load: k row, g-quad
    int a_b = bp * 2 + lr / 64;
    int a_t = t_base + (lr % 64);
    const float* Arow = X + ((size_t)a_b * Tn + a_t) * Dn;

    for (int kt = 0; kt < Dn; kt += 16) {
        float4 a4a = *(const float4*)(Arow + kt + lk * 8);
        float4 a4b = *(const float4*)(Arow + kt + lk * 8 + 4);
        float4 b4  = *(const float4*)(Bmat + (size_t)(kt + bk) * NPADn + g0 + bg * 4);
        __syncthreads();
        As[lk*8+0][lr] = a4a.x; As[lk*8+1][lr] = a4a.y;
        As[lk*8+2][lr] = a4a.z; As[lk*8+3][lr] = a4a.w;
        As[lk*8+4][lr] = a4b.x; As[lk*8+5][lr] = a4b.y;
        As[lk*8+6][lr] = a4b.z; As[lk*8+7][lr] = a4b.w;
        *(float4*)&Bs[bk][bg*4] = b4;
        __syncthreads();
        #pragma unroll
        for (int kk = 0; kk < 16; ++kk) {
            float4 af0 = *(const float4*)&As[kk][ty*8];
            float4 af1 = *(const float4*)&As[kk][ty*8+4];
            float4 bf  = *(const float4*)&Bs[kk][tx*4];
            acc[0][0] += af0.x*bf.x; acc[0][1] += af0.x*bf.y; acc[0][2] += af0.x*bf.z; acc[0][3] += af0.x*bf.w;
            acc[1][0] += af0.y*bf.x; acc[1][1] += af0.y*bf.y; acc[1][2] += af0.y*bf.z; acc[1][3] += af0.y*bf.w;
            acc[2][0] += af0.z*bf.x; acc[2][1] += af0.z*bf.y; acc[2][2] += af0.z*bf.z; acc[2][3] += af0.z*bf.w;
            acc[3][0] += af0.w*bf.x; acc[3][1] += af0.w*bf.y; acc[3][2] += af0.w*bf.z; acc[3][3] += af0.w*bf.w;
            acc[4][0] += af1.x*bf.x; acc[4][1] += af1.x*bf.y; acc[4][2] += af1.x*bf.z; acc[4][3] += af1.x*bf.w;
            acc[5][0] += af1.y*bf.x; acc[5][1] += af1.y*bf.y; acc[5][2] += af1.y*bf.z; acc[5][3] += af1.y*bf.w;
            acc[6][0] += af1.z*bf.x; acc[6][1] += af1.z*bf.y; acc[6][2] += af1.z*bf.z; acc[6][3] += af1.z*bf.w;
            acc[7][0] += af1.w*bf.x; acc[7][1] += af1.w*bf.y; acc[7][2] += af1.w*bf.z; acc[7][3] += af1.w*bf.w;
        }
    }
    #pragma unroll
    for (int ii = 0; ii < 8; ++ii) {
        int r = ty * 8 + ii;
        int b = bp * 2 + r / 64;
        int tloc = r % 64;
        #pragma unroll
        for (int jj = 0; jj < 4; ++jj) {
            int g = g0 + tx * 4 + jj;
            if (g < G4n) {
                int k = g % Hn, q = g / Hn;
                G[(((size_t)d*Bn + b)*TCn + tloc)*G4n + k*4 + q] = acc[ii][jj] + bsum[d*G4n + g];
            }
        }
    }
}

// ---------------- LSTM recurrence for one time-chunk ----------------
// grid: 64 WGs (one per (dir, batch-pair)), 1024 threads = 16 waves = 4/SIMD.
// thread = (k = tid&255, part = tid>>8); part splits j in 4 slices of 50;
// each thread accumulates gate-quad k for BOTH batch elems over its j slice.
__global__ __launch_bounds__(1024, 4) void rec_kernel(const float* __restrict__ mask,
                                                      float* __restrict__ ws, int chunk) {
    const float* WhhP = ws + OFF_WHHP;
    const float* G = ws + OFF_G;
    float* Hcat = ws + OFF_HCAT;
    float* hst = ws + OFF_HST;
    float* cst = ws + OFF_CST;
    int w = blockIdx.x;
    int d = w / 32;
    int pr = w % 32;
    int b0 = pr * 2;
    int k = threadIdx.x & 255;
    int part = threadIdx.x >> 8;
    int bb = b0 + part;                      // reducer's batch elem (part<2 only)
    __shared__ float hbuf[2][2][208];
    __shared__ float4 partial[4][2][208];
    float hr = 0.f, cr = 0.f;
    if (part < 2 && k < Hn) {
        hr = hst[(size_t)(d*Bn + bb)*Hn + k];
        cr = cst[(size_t)(d*Bn + bb)*Hn + k];
        hbuf[0][part][k] = hr;
    }
    __syncthreads();
    int jbase = part * 50;
    const float* Wp = WhhP + (size_t)d*Hn*Hn*4 + (size_t)jbase*Hn*4 + k*4;
    int cur = 0;
    for (int s = 0; s < TCn; ++s) {
        int tg, tloc;
        if (d == 0) { tloc = s; tg = chunk * TCn + s; }
        else        { tloc = TCn - 1 - s; tg = Tn - 1 - (chunk * TCn + s); }
        float m_ = 0.f; float4 gpre = {0.f,0.f,0.f,0.f};
        if (part < 2 && k < Hn) {   // prefetch gate-input + mask; consumed after barrier
            m_ = mask[(size_t)bb * Tn + tg];
            gpre = *(const float4*)(G + (((size_t)d*Bn + bb)*TCn + tloc)*G4n + k*4);
        }
        if (k < Hn) {
            float4 acc0 = {0.f,0.f,0.f,0.f}, acc1 = {0.f,0.f,0.f,0.f};
            #pragma unroll 5
            for (int jj = 0; jj < 50; ++jj) {
                float4 w4 = *(const float4*)(Wp + (size_t)jj*Hn*4);
                float h0 = hbuf[cur][0][jbase + jj];
                float h1 = hbuf[cur][1][jbase + jj];
                acc0.x += w4.x*h0; acc0.y += w4.y*h0; acc0.z += w4.z*h0; acc0.w += w4.w*h0;
                acc1.x += w4.x*h1; acc1.y += w4.y*h1; acc1.z += w4.z*h1; acc1.w += w4.w*h1;
            }
            partial[part][0][k] = acc0;
            partial[part][1][k] = acc1;
        }
        __syncthreads();
        if (part < 2 && k < Hn) {
            float4 s0 = partial[0][part][k];
            float4 s1 = partial[1][part][k];
            float4 s2 = partial[2][part][k];
            float4 s3 = partial[3][part][k];
            float gx = gpre.x + ((s0.x + s1.x) + (s2.x + s3.x));
            float gy = gpre.y + ((s0.y + s1.y) + (s2.y + s3.y));
            float gz = gpre.z + ((s0.z + s1.z) + (s2.z + s3.z));
            float gw = gpre.w + ((s0.w + s1.w) + (s2.w + s3.w));
            float i_ = sigf(gx), f_ = sigf(gy), gg = tanhf(gz), o_ = sigf(gw);
            float cn = f_ * cr + i_ * gg;
            float hn = o_ * tanhf(cn);
            cr = m_ * cn + (1.f - m_) * cr;
            hr = m_ * hn + (1.f - m_) * hr;
            hbuf[cur ^ 1][part][k] = hr;
            Hcat[((size_t)bb * Tn + tg) * (2*Hn) + d*Hn + k] = hr;
        }
        __syncthreads();
        cur ^= 1;
    }
    if (part < 2 && k < Hn) {
        hst[(size_t)(d*Bn + bb)*Hn + k] = hr;
        cst[(size_t)(d*Bn + bb)*Hn + k] = cr;
    }
}

// ---------------- emissions: E = (Hcat @ Wl^T + bl) * mask ----------------
// grid: 256 WGs x 128 rows each
__global__ __launch_bounds__(256) void emis_kernel(const float* __restrict__ mask,
                                                   const float* __restrict__ Wl,
                                                   const float* __restrict__ bl,
                                                   float* __restrict__ ws) {
    const float* Hcat = ws + OFF_HCAT;
    float* E = ws + OFF_E;
    __shared__ float Wls[Ln * 404];
    __shared__ float Hs[16 * 404];
    int tid = threadIdx.x;
    for (int i = tid; i < Ln * 100; i += 256) {
        int l = i / 100, k4 = i % 100;
        *(float4*)&Wls[l*404 + k4*4] = *(const float4*)(Wl + (size_t)l*Dn + k4*4);
    }
    int rbase = blockIdx.x * 128;
    for (int sub = 0; sub < 8; ++sub) {
        int r0 = rbase + sub * 16;
        __syncthreads();
        for (int i = tid; i < 16 * 100; i += 256) {
            int r = i / 100, k4 = i % 100;
            *(float4*)&Hs[r*404 + k4*4] = *(const float4*)(Hcat + (size_t)(r0 + r)*Dn + k4*4);
        }
        __syncthreads();
        for (int o = tid; o < 16 * Ln; o += 256) {
            int r = o / Ln, l = o % Ln;
            float acc = 0.f;
            #pragma unroll 4
            for (int k4 = 0; k4 < 100; ++k4) {
                float4 h = *(const float4*)&Hs[r*404 + k4*4];
                float4 wv = *(const float4*)&Wls[l*404 + k4*4];
                acc += h.x*wv.x + h.y*wv.y + h.z*wv.z + h.w*wv.w;
            }
            int row = r0 + r;            // row == b*T + t
            float m = mask[row];
            E[(size_t)row * Ln + l] = (acc + bl[l]) * m;
        }
    }
}

// ---------------- CRF forward (logZ) + numerator ----------------
__global__ __launch_bounds__(64) void crf_kernel(const float* __restrict__ mask,
                                                 const int* __restrict__ labels,
                                                 const float* __restrict__ trans,
                                                 const float* __restrict__ start,
                                                 const float* __restrict__ endv,
                                                 float* __restrict__ ws) {
    int b = blockIdx.x;
    int l = threadIdx.x;
    const float* E = ws + OFF_E;
    float* part = ws + OFF_PART;
    __shared__ float tr[Ln * Ln];
    __shared__ float al[Ln];
    for (int i = l; i < Ln * Ln; i += 64) tr[i] = trans[i];
    float alpha = -1e30f;
    if (l < Ln) { alpha = start[l] + E[((size_t)b * Tn) * Ln + l]; al[l] = alpha; }
    __syncthreads();
    for (int t = 1; t < Tn; ++t) {
        float mt = mask[(size_t)b * Tn + t];
        if (mt > 0.f) {               // wave-uniform branch
            float nv = alpha;
            if (l < Ln) {
                float v[Ln]; float mx = -1e30f;
                #pragma unroll
                for (int j = 0; j < Ln; ++j) { v[j] = al[j] + tr[j*Ln + l]; mx = fmaxf(mx, v[j]); }
                float s = 0.f;
                #pragma unroll
                for (int j = 0; j < Ln; ++j) s += __expf(v[j] - mx);
                nv = mx + __logf(s) + E[((size_t)b * Tn + t) * Ln + l];
            }
            __syncthreads();
            if (l < Ln) { al[l] = nv; alpha = nv; }
            __syncthreads();
        }
    }
    float v = (l < Ln) ? alpha + endv[l] : -1e30f;
    float mx = v;
    for (int off = 32; off; off >>= 1) mx = fmaxf(mx, __shfl_xor(mx, off));
    float s = (l < Ln) ? __expf(v - mx) : 0.f;
    for (int off = 32; off; off >>= 1) s += __shfl_xor(s, off);
    float logZ = mx + __logf(s);
    // numerator (parallel over t, wave reduce)
    float psum = 0.f, plen = 0.f;
    for (int t = l; t < Tn; t += 64) {
        float mt = mask[(size_t)b * Tn + t];
        plen += mt;
        if (t >= 1 && mt > 0.f) {
            int lt = labels[(size_t)b * Tn + t];
            int lp = labels[(size_t)b * Tn + t - 1];
            psum += E[((size_t)b * Tn + t) * Ln + lt] + tr[lp * Ln + lt];
        }
    }
    for (int off = 32; off; off >>= 1) { psum += __shfl_xor(psum, off); plen += __shfl_xor(plen, off); }
    if (l == 0) {
        int last = (int)(plen + 0.5f) - 1;
        int l0 = labels[(size_t)b * Tn];
        int yl = labels[(size_t)b * Tn + last];
        float num = start[l0] + E[((size_t)b * Tn) * Ln + l0] + psum + endv[yl];
        part[b] = num - logZ;
    }
}

// ---------------- Viterbi ----------------
__global__ __launch_bounds__(64) void vit_kernel(const float* __restrict__ mask,
                                                 const float* __restrict__ trans,
                                                 const float* __restrict__ start,
                                                 const float* __restrict__ endv,
                                                 float* __restrict__ ws,
                                                 float* __restrict__ out) {
    int b = blockIdx.x;
    int l = threadIdx.x;
    const float* E = ws + OFF_E;
    __shared__ float tr[Ln * Ln];
    __shared__ float dl[Ln];
    __shared__ unsigned char ptrs[Tn][Ln];
    __shared__ unsigned char ys[Tn];
    for (int i = l; i < Ln * Ln; i += 64) tr[i] = trans[i];
    float delta = -1e30f;
    if (l < Ln) { delta = start[l] + E[((size_t)b * Tn) * Ln + l]; dl[l] = delta; }
    __syncthreads();
    for (int t = 1; t < Tn; ++t) {
        float mt = mask[(size_t)b * Tn + t];
        float nd = delta; int np = (l < Ln) ? l : 0;
        if (l < Ln && mt > 0.f) {
            float best = -1e30f; int ba = 0;
            #pragma unroll
            for (int j = 0; j < Ln; ++j) {
                float c = dl[j] + tr[j * Ln + l];
                if (c > best) { best = c; ba = j; }  // strict > keeps first index (jnp.argmax)
            }
            nd = best + E[((size_t)b * Tn + t) * Ln + l];
            np = ba;
        }
        __syncthreads();
        if (l < Ln) { dl[l] = nd; ptrs[t][l] = (unsigned char)np; delta = nd; }
        __syncthreads();
    }
    if (l == 0) {
        float best = -1e30f; int y = 0;
        for (int j = 0; j < Ln; ++j) { float c = dl[j] + endv[j]; if (c > best) { best = c; y = j; } }
        ys[Tn - 1] = (unsigned char)y;
        for (int t = Tn - 1; t >= 1; --t) { y = ptrs[t][y]; ys[t - 1] = (unsigned char)y; }
    }
    __syncthreads();
    for (int t = l; t < Tn; t += 64) {
        float mt = mask[(size_t)b * Tn + t];
        out[1 + (size_t)b * Tn + t] = (mt > 0.f) ? (float)ys[t] : 0.f;
    }
}

// ---------------- finalize loss ----------------
__global__ __launch_bounds__(64) void fin_kernel(float* __restrict__ ws, float* __restrict__ out) {
    const float* part = ws + OFF_PART;
    int l = threadIdx.x;
    float v = (l < Bn) ? part[l] : 0.f;
    for (int off = 32; off; off >>= 1) v += __shfl_xor(v, off);
    if (l == 0) out[0] = -v / (float)Bn;
}

extern "C" void kernel_launch(void* const* d_in, const int* in_sizes, int n_in,
                              void* d_out, int out_size, void* d_ws, size_t ws_size,
                              hipStream_t stream) {
    (void)in_sizes; (void)n_in; (void)out_size; (void)ws_size;
    const float* X      = (const float*)d_in[0];
    const float* mask   = (const float*)d_in[1];
    const int*   labels = (const int*)d_in[2];
    const float* Wih_f  = (const float*)d_in[3];
    const float* Whh_f  = (const float*)d_in[4];
    const float* bih_f  = (const float*)d_in[5];
    const float* bhh_f  = (const float*)d_in[6];
    const float* Wih_b  = (const float*)d_in[7];
    const float* Whh_b  = (const float*)d_in[8];
    const float* bih_b  = (const float*)d_in[9];
    const float* bhh_b  = (const float*)d_in[10];
    const float* Wl     = (const float*)d_in[11];
    const float* bl     = (const float*)d_in[12];
    const float* trans  = (const float*)d_in[13];
    const float* start  = (const float*)d_in[14];
    const float* endv   = (const float*)d_in[15];
    float* ws  = (float*)d_ws;
    float* out = (float*)d_out;

    prep_kernel<<<128, 256, 0, stream>>>(Wih_f, Whh_f, bih_f, bhh_f,
                                         Wih_b, Whh_b, bih_b, bhh_b, ws);
    for (int c = 0; c < NCH; ++c) {
        gemm_kernel<<<dim3(13, 32, 2), 256, 0, stream>>>(X, ws, c);
        rec_kernel<<<64, 1024, 0, stream>>>(mask, ws, c);
    }
    emis_kernel<<<256, 256, 0, stream>>>(mask, Wl, bl, ws);
    crf_kernel<<<64, 64, 0, stream>>>(mask, labels, trans, start, endv, ws);
    vit_kernel<<<64, 64, 0, stream>>>(mask, trans, start, endv, ws, out);
    fin_kernel<<<1, 64, 0, stream>>>(ws, out);
}